// Round 13
// baseline (32380.682 us; speedup 1.0000x reference)
//
#include <hip/hip_runtime.h>
#include <math.h>

typedef float v4 __attribute__((ext_vector_type(4)));

#define NB 256
#define LATD 128
#define UPS 64
#define H 512
#define V 25
#define TS 500
#define UPH 288      // up rows staged in LDS (multiple of 8)
#define NBLK 256
#define NGRP 16
#define GSZ (NBLK / NGRP)

// ---- float offsets in workspace ----
#define OFF_HP     0                         // hP[256][512]
#define OFF_UCTX   131072                    // uctx[256][64]
#define OFF_LGP    147456                    // lgp[8][256][25]
#define OFF_EGI    198656                    // Egi2[25][1536]
#define OFF_WHHQ   237056                    // Whh_q[128][1536][4]
#define OFF_WCATQ  1023488                   // Wcat_q[128][512][4]
#define OFF_WFOLDQ 1285632                   // Wfold_q[16][512][4]
#define OFF_WMQ    1318400                   // Wm_q2[128][64][4]
#define OFF_BCAT2  1351168                   // bcat2[512]
#define OFF_BAR    1351680                   // barrier ints (2048)

__device__ __forceinline__ float dot4(v4 a, v4 b) {
    return a.x * b.x + a.y * b.y + a.z * b.z + a.w * b.w;
}

// ---- MALL-coherent bulk access helpers (proven r5-r11) ----
// RULE: never consume a pull result before wait_pull().
__device__ __forceinline__ float pullf(const float* p) {
    float r;
    asm volatile("global_load_dword %0, %1, off sc0 sc1" : "=v"(r) : "v"(p));
    return r;
}
__device__ __forceinline__ v4 pull4(const float* p) {
    v4 r;
    asm volatile("global_load_dwordx4 %0, %1, off sc0 sc1" : "=v"(r) : "v"(p));
    return r;
}
__device__ __forceinline__ void pushf(float* p, float x) {
    asm volatile("global_store_dword %0, %1, off sc0 sc1" :: "v"(p), "v"(x));
}
__device__ __forceinline__ void wait_pull() {
    asm volatile("s_waitcnt vmcnt(0)" ::: "memory");
    __builtin_amdgcn_sched_barrier(0);
}

// ---------------- init kernels (unchanged from r6) ----------------

__global__ void k_init_egi(const float* __restrict__ embed, const float* __restrict__ W_ih,
                           const float* __restrict__ b_ih, float* __restrict__ Egi2) {
    int idx = blockIdx.x * 256 + threadIdx.x;
    if (idx >= V * 3 * H) return;
    int v = idx % V, n = idx / V;
    const float* e = embed + (size_t)v * H;
    const float* wr = W_ih + (size_t)n * H;
    float acc = b_ih[n];
    for (int k = 0; k < H; ++k) acc += e[k] * wr[k];
    Egi2[(size_t)v * 1536 + n] = acc;
}

__global__ void k_init_h0(const float* __restrict__ latent, const float* __restrict__ W_hid,
                          const float* __restrict__ b_hid, float* __restrict__ hP) {
    int b = blockIdx.x, j = threadIdx.x;
    const float* l = latent + (size_t)b * LATD;
    const float* wr = W_hid + (size_t)j * LATD;
    float acc = b_hid[j];
    for (int k = 0; k < LATD; ++k) acc += l[k] * wr[k];
    hP[(size_t)b * H + j] = acc;
}

__global__ void k_pack_whh(const float* __restrict__ W_hh, float* __restrict__ Whh_q) {
    int idx = blockIdx.x * 256 + threadIdx.x;
    if (idx >= 1536 * 128) return;
    int k4 = idx & 127, row = idx >> 7;
    v4 val = *(const v4*)(W_hh + (size_t)row * H + k4 * 4);
    *(v4*)(Whh_q + ((size_t)k4 * 1536 + row) * 4) = val;
}

__global__ void k_pack_wcat(const float* __restrict__ W_cat, float* __restrict__ Wcat_q) {
    int idx = blockIdx.x * 256 + threadIdx.x;
    if (idx >= 512 * 128) return;
    int k4 = idx & 127, row = idx >> 7;
    v4 val = *(const v4*)(W_cat + (size_t)row * (2 * H) + k4 * 4);
    *(v4*)(Wcat_q + ((size_t)k4 * 512 + row) * 4) = val;
}

__global__ void k_init_fold(const float* __restrict__ W_cat, const float* __restrict__ W_mem,
                            float* __restrict__ Wfold_q) {
    int idx = blockIdx.x * 256 + threadIdx.x;
    if (idx >= H * UPS) return;
    int u = idx & 63, j = idx >> 6;
    float acc = 0.f;
    for (int k = 0; k < H; ++k)
        acc += W_cat[(size_t)j * (2 * H) + H + k] * W_mem[(size_t)k * UPS + u];
    Wfold_q[((u >> 2) * 512 + j) * 4 + (u & 3)] = acc;
}

__global__ void k_init_bcat(const float* __restrict__ W_cat, const float* __restrict__ b_mem,
                            const float* __restrict__ b_cat, float* __restrict__ bcat2) {
    int j = blockIdx.x * 256 + threadIdx.x;
    if (j >= H) return;
    float acc = b_cat[j];
    for (int k = 0; k < H; ++k) acc += W_cat[(size_t)j * (2 * H) + H + k] * b_mem[k];
    bcat2[j] = acc;
}

__global__ void k_pack_wmem(const float* __restrict__ W_mem, float* __restrict__ Wm_q2) {
    int idx = blockIdx.x * 256 + threadIdx.x;
    if (idx >= 128 * 64) return;
    int u = idx & 63, k4 = idx >> 6;
    v4 val;
    val.x = W_mem[(size_t)(k4 * 4 + 0) * UPS + u];
    val.y = W_mem[(size_t)(k4 * 4 + 1) * UPS + u];
    val.z = W_mem[(size_t)(k4 * 4 + 2) * UPS + u];
    val.w = W_mem[(size_t)(k4 * 4 + 3) * UPS + u];
    *(v4*)(Wm_q2 + ((size_t)k4 * 64 + u) * 4) = val;
}

__global__ void k_init_bar(int* __restrict__ bar) {
    int i = blockIdx.x * 1024 + threadIdx.x;
    if (i < 2048) bar[i] = 0;
}

// ---------------- grid barrier: r6 semantics + per-group gen fan-out (r11-proven) --------

__device__ __forceinline__ void grid_barrier(int* bar, int epoch) {
    asm volatile("s_waitcnt vmcnt(0)" ::: "memory");  // drain asm pushes of this wave
    __syncthreads();
    asm volatile("" ::: "memory");
    if (threadIdx.x == 0) {
        const int grp = blockIdx.x & (NGRP - 1);
        int* gcnt = bar + grp * 32;
        int* root = bar + NGRP * 32;
        int* gens = bar + NGRP * 32 + 32;   // 16 lines, stride 32 ints
        int a = __hip_atomic_fetch_add(gcnt, 1, __ATOMIC_RELEASE, __HIP_MEMORY_SCOPE_AGENT);
        if (a == epoch * GSZ + (GSZ - 1)) {
            int r = __hip_atomic_fetch_add(root, 1, __ATOMIC_RELEASE, __HIP_MEMORY_SCOPE_AGENT);
            if (r == epoch * NGRP + (NGRP - 1)) {
                for (int g2 = 0; g2 < NGRP; ++g2)
                    __hip_atomic_store(gens + g2 * 32, epoch + 1, __ATOMIC_RELEASE,
                                       __HIP_MEMORY_SCOPE_AGENT);
            }
        }
        while (__hip_atomic_load(gens + grp * 32, __ATOMIC_RELAXED, __HIP_MEMORY_SCOPE_AGENT) <= epoch)
            __builtin_amdgcn_s_sleep(1);
    }
    asm volatile("" ::: "memory");
    __syncthreads();
}

// ---------------- persistent main kernel (1024 threads; VGPR cap derived from wg size) ----
// NOTE: plain __launch_bounds__(1024): backend caps VGPR at 128 (16 waves must fit one CU).
// r10's (1024,4) forced VGPR=64 -> spills; r12's (1024,1) allowed >128 -> unlaunchable.

__global__ __launch_bounds__(1024) void k_main(
    const float* __restrict__ up, const float* __restrict__ b_hh,
    const float* __restrict__ W_out, const float* __restrict__ b_out,
    float* __restrict__ out, float* __restrict__ ws)
{
    float* hP    = ws + OFF_HP;
    float* uctxB = ws + OFF_UCTX;
    float* lgp   = ws + OFF_LGP;
    const float* Egi2    = ws + OFF_EGI;
    const float* Whh_q   = ws + OFF_WHHQ;
    const float* Wcat_q  = ws + OFF_WCATQ;
    const float* Wfold_q = ws + OFF_WFOLDQ;
    const float* Wm_q2   = ws + OFF_WMQ;
    const float* bcat2   = ws + OFF_BCAT2;
    int*   bar   = (int*)(ws + OFF_BAR);

    const int tid = threadIdx.x;
    const int bid = blockIdx.x;
    const int jx = bid & 7;          // j-slice (XCD-pinned)
    const int bs = bid >> 3;         // batch slice: rows bs*8 .. +7
    const int w = tid >> 6, lane = tid & 63;
    const int g = w >> 3;            // GEMM row group (rows g*4..+3)
    const int c = w & 7;             // GEMM k-chunk (16 k4)
    const int jg = lane;
    const int j = jx * 64 + jg;
    const int b2 = jx * 32 + bs;     // attention row

    const v4* wq4 = (const v4*)Whh_q;
    const v4* wc4 = (const v4*)Wcat_q;
    const v4* wf4 = (const v4*)Wfold_q;
    const v4* wm4 = (const v4*)Wm_q2;

    __shared__ float up_lds[UPH * 68];                 // 78.3 KB, pad-68 rows
    __shared__ __align__(16) float s_h[128 * 8 * 4];   // 16 KB
    __shared__ float s_red[16 * 64 * 13];              // 53.2 KB (P1; P3 reuses)
    __shared__ float s_lg[8 * 26];
    __shared__ int   s_id[8];
    __shared__ __align__(16) float s_hrow[512];
    __shared__ float s_part[8 * 64];
    __shared__ __align__(16) float s_hp[64];
    __shared__ float s_ctx[8 * 64];
    __shared__ float s_mw[8], s_Sw[8];
    __shared__ __align__(16) float s_uctx[512];
    __shared__ float s_cc[64 * 9];

    v4* s_h4 = (v4*)s_h;
    const v4* s_u4 = (const v4*)s_uctx;

    const int k4s = tid >> 3, blp = tid & 7;           // h-tile mapping (1024 = 128x8)
    const int lgb = tid / 25, lgv = tid - lgb * 25;    // logits lane mapping (tid<200)

    int ep = 0;

    // ---- prologue: stage up rows [0,UPH) + h0 tile into LDS ----
    for (int i = tid; i < UPH * 16; i += 1024) {
        const int tt = i >> 4, u4 = i & 15;
        v4 val = *(const v4*)(up + ((size_t)b2 * TS + tt) * UPS + u4 * 4);
        *(v4*)(up_lds + tt * 68 + u4 * 4) = val;
    }
    {
        v4 aa = pull4(hP + (size_t)(bs * 8 + blp) * H + k4s * 4);
        wait_pull();
        s_h4[k4s * 8 + blp] = aa;
    }
    grid_barrier(bar, ep++);

    for (int t = 0; t < TS; ++t) {
        // ================= P1: logits reduce + argmax + GRU (r10 verbatim) =========
        if (t > 0) {
            if (tid < 200) {
                const int b = bs * 8 + lgb;
                float p0 = pullf(lgp + ((size_t)0 * 256 + b) * 25 + lgv);
                float p1 = pullf(lgp + ((size_t)1 * 256 + b) * 25 + lgv);
                float p2 = pullf(lgp + ((size_t)2 * 256 + b) * 25 + lgv);
                float p3 = pullf(lgp + ((size_t)3 * 256 + b) * 25 + lgv);
                float p4 = pullf(lgp + ((size_t)4 * 256 + b) * 25 + lgv);
                float p5 = pullf(lgp + ((size_t)5 * 256 + b) * 25 + lgv);
                float p6 = pullf(lgp + ((size_t)6 * 256 + b) * 25 + lgv);
                float p7 = pullf(lgp + ((size_t)7 * 256 + b) * 25 + lgv);
                wait_pull();
                float s = ((p0 + p1) + (p2 + p3)) + ((p4 + p5) + (p6 + p7)) + b_out[lgv];
                s_lg[lgb * 26 + lgv] = s;
                if (jx == 0) out[((size_t)b * V + lgv) * TS + (t - 1)] = s;
            }
            __syncthreads();
            if (tid < 8) {
                float best = s_lg[tid * 26];
                int bi = 0;
                for (int v = 1; v < V; ++v) {
                    float x = s_lg[tid * 26 + v];
                    if (x > best) { best = x; bi = v; }
                }
                s_id[tid] = bi;
            }
            __syncthreads();
        } else {
            if (tid < 8) s_id[tid] = 0;   // SOS
            __syncthreads();
        }
        // GRU GEMM: wave (g,c) -> rows g*4..+3, k4 in [c*16,+16)
        {
            float ar[4] = {0.f, 0.f, 0.f, 0.f};
            float az[4] = {0.f, 0.f, 0.f, 0.f};
            float an[4] = {0.f, 0.f, 0.f, 0.f};
            const int kbase = c * 16;
#pragma unroll 4
            for (int kk = 0; kk < 16; ++kk) {
                const int k4 = kbase + kk;
                const v4 wr = wq4[k4 * 1536 + j];
                const v4 wz = wq4[k4 * 1536 + 512 + j];
                const v4 wn = wq4[k4 * 1536 + 1024 + j];
#pragma unroll
                for (int r = 0; r < 4; ++r) {
                    const v4 hv = s_h4[k4 * 8 + g * 4 + r];
                    ar[r] += dot4(hv, wr);
                    az[r] += dot4(hv, wz);
                    an[r] += dot4(hv, wn);
                }
            }
            const int base = w * 832 + jg * 13;
#pragma unroll
            for (int r = 0; r < 4; ++r) {
                s_red[base + r * 3 + 0] = ar[r];
                s_red[base + r * 3 + 1] = az[r];
                s_red[base + r * 3 + 2] = an[r];
            }
        }
        __syncthreads();
        if (tid < 512) {
            const int bl = tid >> 6, jg2 = tid & 63;
            const int gg = bl >> 2, rr = bl & 3;
            const int j2 = jx * 64 + jg2;
            float sr = 0.f, sz = 0.f, sn = 0.f;
#pragma unroll
            for (int c2 = 0; c2 < 8; ++c2) {
                const int base2 = (gg * 8 + c2) * 832 + jg2 * 13 + rr * 3;
                sr += s_red[base2 + 0];
                sz += s_red[base2 + 1];
                sn += s_red[base2 + 2];
            }
            const int id = s_id[bl];
            const float gir = Egi2[(size_t)id * 1536 + j2];
            const float giz = Egi2[(size_t)id * 1536 + 512 + j2];
            const float gin = Egi2[(size_t)id * 1536 + 1024 + j2];
            sr += b_hh[j2] + gir;
            sz += b_hh[512 + j2] + giz;
            sn += b_hh[1024 + j2];
            const float r = 1.f / (1.f + __expf(-sr));
            const float z = 1.f / (1.f + __expf(-sz));
            const float n = tanhf(gin + r * sn);
            const float hold = s_h[((j2 >> 2) * 8 + bl) * 4 + (j2 & 3)];
            pushf(hP + (size_t)(bs * 8 + bl) * H + j2, (1.f - z) * n + z * hold);
        }
        grid_barrier(bar, ep++);

        // ================= P2: attention for row b2 (r10 verbatim) ==================
        if (tid < 512) {
            float hv_ = pullf(hP + (size_t)b2 * H + tid);
            wait_pull();
            s_hrow[tid] = hv_;
        }
        __syncthreads();
        if (w < 8) {
            const v4* sr4 = (const v4*)s_hrow;
            float a = 0.f;
#pragma unroll 4
            for (int i = 0; i < 16; ++i) {
                const int k4 = w * 16 + i;
                a += dot4(sr4[k4], wm4[k4 * 64 + lane]);
            }
            s_part[w * 64 + lane] = a;
        }
        __syncthreads();
        if (w == 0) {
            float a = s_part[lane];
            for (int i = 1; i < 8; ++i) a += s_part[i * 64 + lane];
            s_hp[lane] = a;
        }
        __syncthreads();
        if (w < 8) {
            const int u0 = (lane & 7) * 8;
            const int tsub = lane >> 3;
            v4 hpA = *(const v4*)&s_hp[u0];
            v4 hpB = *(const v4*)&s_hp[u0 + 4];
            float mx = -1e30f, S = 0.f;
            float cx[8] = {0.f, 0.f, 0.f, 0.f, 0.f, 0.f, 0.f, 0.f};
#pragma unroll
            for (int p = 0; p < 8; ++p) {
                const int tt = p * 64 + w * 8 + tsub;
                v4 ua = {0.f, 0.f, 0.f, 0.f}, ub = {0.f, 0.f, 0.f, 0.f};
                float part = 0.f;
                if (tt < TS) {
                    if (tt < UPH) {
                        ua = *(const v4*)(up_lds + tt * 68 + u0);
                        ub = *(const v4*)(up_lds + tt * 68 + u0 + 4);
                    } else {
                        const v4* ur = (const v4*)(up + ((size_t)b2 * TS + tt) * UPS + u0);
                        ua = ur[0];
                        ub = ur[1];
                    }
                    part = dot4(ua, hpA) + dot4(ub, hpB);
                }
                part += __shfl_xor(part, 1);
                part += __shfl_xor(part, 2);
                part += __shfl_xor(part, 4);
                const float s = (tt < TS) ? part : -1e30f;
                float M = s;
                M = fmaxf(M, __shfl_xor(M, 8));
                M = fmaxf(M, __shfl_xor(M, 16));
                M = fmaxf(M, __shfl_xor(M, 32));
                const float mn = fmaxf(mx, M);
                const float alpha = __expf(mx - mn);
                const float e = __expf(s - mn);
                float E = e;
                E += __shfl_xor(E, 8); E += __shfl_xor(E, 16); E += __shfl_xor(E, 32);
                S = S * alpha + E;
                mx = mn;
#pragma unroll
                for (int i = 0; i < 4; ++i) cx[i] = cx[i] * alpha + e * ua[i];
#pragma unroll
                for (int i = 0; i < 4; ++i) cx[4 + i] = cx[4 + i] * alpha + e * ub[i];
            }
#pragma unroll
            for (int i = 0; i < 8; ++i) {
                cx[i] += __shfl_xor(cx[i], 8);
                cx[i] += __shfl_xor(cx[i], 16);
                cx[i] += __shfl_xor(cx[i], 32);
            }
            if (tsub == 0) {
#pragma unroll
                for (int i = 0; i < 8; ++i) s_ctx[w * 64 + u0 + i] = cx[i];
            }
            if (lane == 0) { s_mw[w] = mx; s_Sw[w] = S; }
        }
        __syncthreads();
        if (tid < UPS) {
            float M = s_mw[0];
            for (int i = 1; i < 8; ++i) M = fmaxf(M, s_mw[i]);
            float Sg = 0.f, cc = 0.f;
            for (int i = 0; i < 8; ++i) {
                const float f = __expf(s_mw[i] - M);
                Sg += s_Sw[i] * f;
                cc += s_ctx[i * 64 + tid] * f;
            }
            pushf(uctxB + (size_t)b2 * UPS + tid, cc / Sg);
        }
        grid_barrier(bar, ep++);

        // ================= P3: stage h_new+uctx, concat GEMM, logits (r10 verbatim) ==
        {
            v4 aa = pull4(hP + (size_t)(bs * 8 + blp) * H + k4s * 4);
            float uv = 0.f;
            if (tid < 512) uv = pullf(uctxB + (size_t)(bs * 8 + (tid >> 6)) * UPS + (tid & 63));
            wait_pull();
            s_h4[k4s * 8 + blp] = aa;
            if (tid < 512) {
                const int uu = tid & 63, blu = tid >> 6;
                s_uctx[((uu >> 2) * 8 + blu) * 4 + (uu & 3)] = uv;
            }
        }
        __syncthreads();
        {
            float acc[4] = {0.f, 0.f, 0.f, 0.f};
            const int kbase = c * 16;
#pragma unroll 4
            for (int kk = 0; kk < 16; ++kk) {
                const int k4 = kbase + kk;
                const v4 wv = wc4[k4 * 512 + j];
#pragma unroll
                for (int r = 0; r < 4; ++r)
                    acc[r] += dot4(s_h4[k4 * 8 + g * 4 + r], wv);
            }
#pragma unroll
            for (int ui = 0; ui < 2; ++ui) {
                const int u4 = c * 2 + ui;
                const v4 wv = wf4[u4 * 512 + j];
#pragma unroll
                for (int r = 0; r < 4; ++r)
                    acc[r] += dot4(s_u4[u4 * 8 + g * 4 + r], wv);
            }
            const int base = w * 320 + jg * 5;
#pragma unroll
            for (int r = 0; r < 4; ++r) s_red[base + r] = acc[r];
        }
        __syncthreads();
        if (tid < 512) {
            const int bl = tid >> 6, jg2 = tid & 63;
            const int gg = bl >> 2, rr = bl & 3;
            float a = 0.f;
#pragma unroll
            for (int c2 = 0; c2 < 8; ++c2)
                a += s_red[(gg * 8 + c2) * 320 + jg2 * 5 + rr];
            s_cc[jg2 * 9 + bl] = tanhf(a + bcat2[jx * 64 + jg2]);
        }
        __syncthreads();
        if (tid < 200) {
            float a = 0.f;
            const float* wo = W_out + (size_t)lgv * H + jx * 64;
#pragma unroll 8
            for (int jj = 0; jj < 64; ++jj) a += s_cc[jj * 9 + lgb] * wo[jj];
            pushf(lgp + ((size_t)jx * 256 + (bs * 8 + lgb)) * 25 + lgv, a);
        }
        grid_barrier(bar, ep++);
    }

    // ---- tail: final logits (t = TS-1); pulls fully drained BEFORE use ----
    if (jx == 0 && tid < 200) {
        const int b = bs * 8 + lgb;
        float p0 = pullf(lgp + ((size_t)0 * 256 + b) * 25 + lgv);
        float p1 = pullf(lgp + ((size_t)1 * 256 + b) * 25 + lgv);
        float p2 = pullf(lgp + ((size_t)2 * 256 + b) * 25 + lgv);
        float p3 = pullf(lgp + ((size_t)3 * 256 + b) * 25 + lgv);
        float p4 = pullf(lgp + ((size_t)4 * 256 + b) * 25 + lgv);
        float p5 = pullf(lgp + ((size_t)5 * 256 + b) * 25 + lgv);
        float p6 = pullf(lgp + ((size_t)6 * 256 + b) * 25 + lgv);
        float p7 = pullf(lgp + ((size_t)7 * 256 + b) * 25 + lgv);
        wait_pull();
        float s = ((p0 + p1) + (p2 + p3)) + ((p4 + p5) + (p6 + p7)) + b_out[lgv];
        out[((size_t)b * V + lgv) * TS + (TS - 1)] = s;
    }
}

// ---------------- launcher ----------------

extern "C" void kernel_launch(void* const* d_in, const int* in_sizes, int n_in,
                              void* d_out, int out_size, void* d_ws, size_t ws_size,
                              hipStream_t stream) {
    const float* latent = (const float*)d_in[0];
    const float* up     = (const float*)d_in[1];
    const float* embed  = (const float*)d_in[2];
    const float* W_hid  = (const float*)d_in[3];
    const float* b_hid  = (const float*)d_in[4];
    const float* W_ih   = (const float*)d_in[5];
    const float* b_ih   = (const float*)d_in[6];
    const float* W_hh   = (const float*)d_in[7];
    const float* b_hh   = (const float*)d_in[8];
    const float* W_mem  = (const float*)d_in[9];
    const float* b_mem  = (const float*)d_in[10];
    const float* W_cat  = (const float*)d_in[11];
    const float* b_cat  = (const float*)d_in[12];
    const float* W_out  = (const float*)d_in[13];
    const float* b_out  = (const float*)d_in[14];
    float* out = (float*)d_out;
    float* ws = (float*)d_ws;

    k_init_egi<<<(V * 3 * H + 255) / 256, 256, 0, stream>>>(embed, W_ih, b_ih, ws + OFF_EGI);
    k_init_h0<<<NB, H, 0, stream>>>(latent, W_hid, b_hid, ws + OFF_HP);
    k_pack_whh<<<(1536 * 128 + 255) / 256, 256, 0, stream>>>(W_hh, ws + OFF_WHHQ);
    k_pack_wcat<<<(512 * 128 + 255) / 256, 256, 0, stream>>>(W_cat, ws + OFF_WCATQ);
    k_init_fold<<<(H * UPS + 255) / 256, 256, 0, stream>>>(W_cat, W_mem, ws + OFF_WFOLDQ);
    k_init_bcat<<<(H + 255) / 256, 256, 0, stream>>>(W_cat, b_mem, b_cat, ws + OFF_BCAT2);
    k_pack_wmem<<<(128 * 64 + 255) / 256, 256, 0, stream>>>(W_mem, ws + OFF_WMQ);
    k_init_bar<<<2, 1024, 0, stream>>>((int*)(ws + OFF_BAR));

    k_main<<<NBLK, 1024, 0, stream>>>(up, b_hh, W_out, b_out, out, ws);
}

// Round 14
// 15979.883 us; speedup vs baseline: 2.0263x; 2.0263x over previous
//
#include <hip/hip_runtime.h>
#include <math.h>

typedef float v4 __attribute__((ext_vector_type(4)));

#define NB 256
#define LATD 128
#define UPS 64
#define H 512
#define V 25
#define TS 500
#define UPH 288      // up rows staged in LDS
#define NBLK 256

// ---- float offsets in workspace ----
#define OFF_HP     0                         // hP[256][512]
#define OFF_UCTX   131072                    // uctx[256][64]
#define OFF_LGP    147456                    // lgp[8][256][25]
#define OFF_EGI    198656                    // Egi2[25][1536]
#define OFF_WHHQ   237056                    // Whh_q[128][1536][4]
#define OFF_WCATQ  1023488                   // Wcat_q[128][512][4]
#define OFF_WFOLDQ 1285632                   // Wfold_q[16][512][4]
#define OFF_WMQ    1318400                   // Wm_q2[128][64][4]
#define OFF_BCAT2  1351168                   // bcat2[512]
#define OFF_HF     1351680                   // hFlag[256*16] ints
#define OFF_UF     (OFF_HF + 4096)           // uFlag[256*16] ints
#define OFF_LF     (OFF_UF + 4096)           // lgFlag[256*16] ints

__device__ __forceinline__ float dot4(v4 a, v4 b) {
    return a.x * b.x + a.y * b.y + a.z * b.z + a.w * b.w;
}

// ---- MALL-coherent bulk access helpers (proven r5-r11) ----
// RULE: never consume a pull result before wait_pull().
__device__ __forceinline__ float pullf(const float* p) {
    float r;
    asm volatile("global_load_dword %0, %1, off sc0 sc1" : "=v"(r) : "v"(p));
    return r;
}
__device__ __forceinline__ v4 pull4(const float* p) {
    v4 r;
    asm volatile("global_load_dwordx4 %0, %1, off sc0 sc1" : "=v"(r) : "v"(p));
    return r;
}
__device__ __forceinline__ void pushf(float* p, float x) {
    asm volatile("global_store_dword %0, %1, off sc0 sc1" :: "v"(p), "v"(x));
}
__device__ __forceinline__ void wait_pull() {
    asm volatile("s_waitcnt vmcnt(0)" ::: "memory");
    __builtin_amdgcn_sched_barrier(0);
}

// ---- fine-grained epoch flags (replaces global barrier) ----
// Producer: data pushes -> vmcnt(0) -> __syncthreads -> tid0 RELEASE store.
// Consumer: RELAXED spin (no acquire: data reads use sc0/sc1 cache-bypass pulls).
__device__ __forceinline__ void spin_flag(const int* f, int target) {
    while (__hip_atomic_load(f, __ATOMIC_RELAXED, __HIP_MEMORY_SCOPE_AGENT) < target)
        __builtin_amdgcn_s_sleep(1);
}
__device__ __forceinline__ void set_flag(int* f, int v) {
    __hip_atomic_store(f, v, __ATOMIC_RELEASE, __HIP_MEMORY_SCOPE_AGENT);
}

// ---------------- init kernels (unchanged from r6) ----------------

__global__ void k_init_egi(const float* __restrict__ embed, const float* __restrict__ W_ih,
                           const float* __restrict__ b_ih, float* __restrict__ Egi2) {
    int idx = blockIdx.x * 256 + threadIdx.x;
    if (idx >= V * 3 * H) return;
    int v = idx % V, n = idx / V;
    const float* e = embed + (size_t)v * H;
    const float* wr = W_ih + (size_t)n * H;
    float acc = b_ih[n];
    for (int k = 0; k < H; ++k) acc += e[k] * wr[k];
    Egi2[(size_t)v * 1536 + n] = acc;
}

__global__ void k_init_h0(const float* __restrict__ latent, const float* __restrict__ W_hid,
                          const float* __restrict__ b_hid, float* __restrict__ hP) {
    int b = blockIdx.x, j = threadIdx.x;
    const float* l = latent + (size_t)b * LATD;
    const float* wr = W_hid + (size_t)j * LATD;
    float acc = b_hid[j];
    for (int k = 0; k < LATD; ++k) acc += l[k] * wr[k];
    hP[(size_t)b * H + j] = acc;
}

__global__ void k_pack_whh(const float* __restrict__ W_hh, float* __restrict__ Whh_q) {
    int idx = blockIdx.x * 256 + threadIdx.x;
    if (idx >= 1536 * 128) return;
    int k4 = idx & 127, row = idx >> 7;
    v4 val = *(const v4*)(W_hh + (size_t)row * H + k4 * 4);
    *(v4*)(Whh_q + ((size_t)k4 * 1536 + row) * 4) = val;
}

__global__ void k_pack_wcat(const float* __restrict__ W_cat, float* __restrict__ Wcat_q) {
    int idx = blockIdx.x * 256 + threadIdx.x;
    if (idx >= 512 * 128) return;
    int k4 = idx & 127, row = idx >> 7;
    v4 val = *(const v4*)(W_cat + (size_t)row * (2 * H) + k4 * 4);
    *(v4*)(Wcat_q + ((size_t)k4 * 512 + row) * 4) = val;
}

__global__ void k_init_fold(const float* __restrict__ W_cat, const float* __restrict__ W_mem,
                            float* __restrict__ Wfold_q) {
    int idx = blockIdx.x * 256 + threadIdx.x;
    if (idx >= H * UPS) return;
    int u = idx & 63, j = idx >> 6;
    float acc = 0.f;
    for (int k = 0; k < H; ++k)
        acc += W_cat[(size_t)j * (2 * H) + H + k] * W_mem[(size_t)k * UPS + u];
    Wfold_q[((u >> 2) * 512 + j) * 4 + (u & 3)] = acc;
}

__global__ void k_init_bcat(const float* __restrict__ W_cat, const float* __restrict__ b_mem,
                            const float* __restrict__ b_cat, float* __restrict__ bcat2) {
    int j = blockIdx.x * 256 + threadIdx.x;
    if (j >= H) return;
    float acc = b_cat[j];
    for (int k = 0; k < H; ++k) acc += W_cat[(size_t)j * (2 * H) + H + k] * b_mem[k];
    bcat2[j] = acc;
}

__global__ void k_pack_wmem(const float* __restrict__ W_mem, float* __restrict__ Wm_q2) {
    int idx = blockIdx.x * 256 + threadIdx.x;
    if (idx >= 128 * 64) return;
    int u = idx & 63, k4 = idx >> 6;
    v4 val;
    val.x = W_mem[(size_t)(k4 * 4 + 0) * UPS + u];
    val.y = W_mem[(size_t)(k4 * 4 + 1) * UPS + u];
    val.z = W_mem[(size_t)(k4 * 4 + 2) * UPS + u];
    val.w = W_mem[(size_t)(k4 * 4 + 3) * UPS + u];
    *(v4*)(Wm_q2 + ((size_t)k4 * 64 + u) * 4) = val;
}

__global__ void k_init_flags(int* __restrict__ f) {
    int i = blockIdx.x * 1024 + threadIdx.x;
    if (i < 3 * 4096) f[i] = 0;
}

// ---------------- persistent main kernel (512 threads, flag-synced dataflow) ----------------

__global__ __launch_bounds__(512, 1) void k_main(
    const float* __restrict__ up, const float* __restrict__ b_hh,
    const float* __restrict__ W_out, const float* __restrict__ b_out,
    float* __restrict__ out, float* __restrict__ ws)
{
    float* hP    = ws + OFF_HP;
    float* uctxB = ws + OFF_UCTX;
    float* lgp   = ws + OFF_LGP;
    const float* Egi2    = ws + OFF_EGI;
    const float* Whh_q   = ws + OFF_WHHQ;
    const float* Wcat_q  = ws + OFF_WCATQ;
    const float* Wfold_q = ws + OFF_WFOLDQ;
    const float* Wm_q2   = ws + OFF_WMQ;
    const float* bcat2   = ws + OFF_BCAT2;
    int* hF  = (int*)(ws + OFF_HF);
    int* uF  = (int*)(ws + OFF_UF);
    int* lgF = (int*)(ws + OFF_LF);

    const int tid = threadIdx.x;
    const int bid = blockIdx.x;
    const int jx = bid & 7;          // j-slice (XCD-pinned); bid = bs*8 + jx
    const int bs = bid >> 3;         // batch slice: rows bs*8 .. bs*8+7
    const int jg = tid & 63;         // j within slice (GEMM phases)
    const int wk = tid >> 6;         // k-split wave (GEMM phases)
    const int j = jx * 64 + jg;
    const int w = tid >> 6, lane = tid & 63;   // P2 naming
    const int b2 = jx * 32 + bs;               // P2 batch row (pinned per XCD)

    const v4* wq4 = (const v4*)Whh_q;
    const v4* wc4 = (const v4*)Wcat_q;
    const v4* wf4 = (const v4*)Wfold_q;
    const v4* wm4 = (const v4*)Wm_q2;

    __shared__ __align__(16) float up_lds[UPH * 68];     // 78.3 KB (pad-68)
    __shared__ __align__(16) float s_h[128 * 9 * 4];     // h[k4][bl(9-pad)][4]
    __shared__ float s_red[8 * 64 * 25];                 // partials [wk][jg][25-pad]
    __shared__ __align__(16) float s_uctx[16 * 8 * 4];   // uctx[u4][bl][4]
    __shared__ float s_c[64 * 9];                        // concat [jg][bl(9-pad)]
    __shared__ float s_lg[8 * 26];                       // summed logits [bl][26-pad]
    __shared__ int   s_id[8];
    __shared__ __align__(16) float s_hrow[512];          // P2: h row
    __shared__ float s_part[8][64];
    __shared__ __align__(16) float s_hp[64];
    __shared__ float s_ctx[8][64];
    __shared__ float s_mw[8], s_Sw[8];

    v4* s_h4 = (v4*)s_h;
    const v4* s_u4 = (const v4*)s_uctx;

    const int k4s = tid >> 2, blp = (tid & 3) * 2;       // h-tile staging mapping
    const int lgb = tid / 25, lgv = tid - lgb * 25;      // logits lane mapping (tid<200)

    // ---- prologue: stage up rows [0,UPH) + h0 tile into LDS ----
    for (int i = tid; i < UPH * 16; i += 512) {
        const int tt = i >> 4, u4 = i & 15;
        v4 val = *(const v4*)(up + ((size_t)b2 * TS + tt) * UPS + u4 * 4);
        *(v4*)(up_lds + tt * 68 + u4 * 4) = val;
    }
    {
        v4 aa = pull4(hP + (size_t)(bs * 8 + blp) * H + k4s * 4);
        v4 bb = pull4(hP + (size_t)(bs * 8 + blp + 1) * H + k4s * 4);
        wait_pull();
        s_h4[k4s * 9 + blp] = aa;
        s_h4[k4s * 9 + blp + 1] = bb;
    }
    __syncthreads();

    for (int t = 0; t < TS; ++t) {
        // ================= P1: lgp flags + pull-early + GRU GEMM + argmax + gates =====
        if (t > 0) {
            if (tid < 8) spin_flag(lgF + (bs * 8 + tid) * 16, t);
            __syncthreads();
        }
        float p0, p1, p2, p3, p4, p5, p6, p7;
        if (t > 0 && tid < 200) {
            const int b = bs * 8 + lgb;
            p0 = pullf(lgp + ((size_t)0 * 256 + b) * 25 + lgv);
            p1 = pullf(lgp + ((size_t)1 * 256 + b) * 25 + lgv);
            p2 = pullf(lgp + ((size_t)2 * 256 + b) * 25 + lgv);
            p3 = pullf(lgp + ((size_t)3 * 256 + b) * 25 + lgv);
            p4 = pullf(lgp + ((size_t)4 * 256 + b) * 25 + lgv);
            p5 = pullf(lgp + ((size_t)5 * 256 + b) * 25 + lgv);
            p6 = pullf(lgp + ((size_t)6 * 256 + b) * 25 + lgv);
            p7 = pullf(lgp + ((size_t)7 * 256 + b) * 25 + lgv);
        }
        // GRU GEMM (r11 verbatim): wave wk handles k4 in [wk*16,+16), 8 b in registers
        {
            float a0[8], a1[8], a2[8];
#pragma unroll
            for (int bl = 0; bl < 8; ++bl) { a0[bl] = 0.f; a1[bl] = 0.f; a2[bl] = 0.f; }
            const int kbase = wk * 16;
#pragma unroll 4
            for (int kk = 0; kk < 16; ++kk) {
                const int k4 = kbase + kk;
                const v4 wr = wq4[k4 * 1536 + j];
                const v4 wz = wq4[k4 * 1536 + 512 + j];
                const v4 wn = wq4[k4 * 1536 + 1024 + j];
                const v4* hrow = &s_h4[k4 * 9];
#pragma unroll
                for (int bl = 0; bl < 8; ++bl) {
                    v4 hv = hrow[bl];
                    a0[bl] += dot4(hv, wr);
                    a1[bl] += dot4(hv, wz);
                    a2[bl] += dot4(hv, wn);
                }
            }
            const int rb = wk * 1600 + jg * 25;
#pragma unroll
            for (int bl = 0; bl < 8; ++bl) {
                s_red[rb + bl] = a0[bl];
                s_red[rb + 8 + bl] = a1[bl];
                s_red[rb + 16 + bl] = a2[bl];
            }
        }
        // logits finalize (pull latency hidden under the GEMM above)
        if (t > 0 && tid < 200) {
            wait_pull();
            const int b = bs * 8 + lgb;
            float s = ((p0 + p1) + (p2 + p3)) + ((p4 + p5) + (p6 + p7)) + b_out[lgv];
            s_lg[lgb * 26 + lgv] = s;
            if (jx == 0) out[((size_t)b * V + lgv) * TS + (t - 1)] = s;
        }
        __syncthreads();   // covers s_red + s_lg
        if (tid < 8) {
            if (t > 0) {
                float best = s_lg[tid * 26];
                int bi = 0;
                for (int v = 1; v < V; ++v) {
                    float x = s_lg[tid * 26 + v];
                    if (x > best) { best = x; bi = v; }
                }
                s_id[tid] = bi;
            } else {
                s_id[tid] = 0;   // SOS
            }
        }
        __syncthreads();
        // gate math (r11 verbatim)
        {
            const int bl = tid >> 6, jg2 = tid & 63;
            const int j2 = jx * 64 + jg2;
            float sr = 0.f, sz = 0.f, sn = 0.f;
#pragma unroll
            for (int wk2 = 0; wk2 < 8; ++wk2) {
                const int base = wk2 * 1600 + jg2 * 25;
                sr += s_red[base + bl];
                sz += s_red[base + 8 + bl];
                sn += s_red[base + 16 + bl];
            }
            const int id = s_id[bl];
            const float gir = Egi2[(size_t)id * 1536 + j2];
            const float giz = Egi2[(size_t)id * 1536 + 512 + j2];
            const float gin = Egi2[(size_t)id * 1536 + 1024 + j2];
            sr += b_hh[j2] + gir;
            sz += b_hh[512 + j2] + giz;
            sn += b_hh[1024 + j2];
            const float r = 1.f / (1.f + __expf(-sr));
            const float z = 1.f / (1.f + __expf(-sz));
            const float n = tanhf(gin + r * sn);
            const float hold = s_h[((j2 >> 2) * 9 + bl) * 4 + (j2 & 3)];
            pushf(hP + (size_t)(bs * 8 + bl) * H + j2, (1.f - z) * n + z * hold);
        }
        wait_pull();
        __syncthreads();
        if (tid == 0) set_flag(hF + bid * 16, t + 1);

        // ================= P2: attention for row b2 (r11 math; up from LDS) ==========
        {
            if (tid < 8) spin_flag(hF + ((b2 >> 3) * 8 + tid) * 16, t + 1);
            __syncthreads();
            float hv_ = pullf(hP + (size_t)b2 * H + tid);
            wait_pull();
            s_hrow[tid] = hv_;
            __syncthreads();
            const v4* sr4 = (const v4*)s_hrow;
            {
                float a = 0.f;
#pragma unroll 4
                for (int i = 0; i < 16; ++i) {
                    const int k4 = w * 16 + i;
                    a += dot4(sr4[k4], wm4[k4 * 64 + lane]);
                }
                s_part[w][lane] = a;
            }
            __syncthreads();
            if (w == 0) {
                float a = s_part[0][lane];
                for (int i = 1; i < 8; ++i) a += s_part[i][lane];
                s_hp[lane] = a;
            }
            __syncthreads();

            const int u0 = (lane & 7) * 8;
            const int tsub = lane >> 3;
            v4 hpA = *(const v4*)&s_hp[u0];
            v4 hpB = *(const v4*)&s_hp[u0 + 4];
            float mx = -1e30f, S = 0.f;
            float cx[8] = {0.f, 0.f, 0.f, 0.f, 0.f, 0.f, 0.f, 0.f};
#pragma unroll
            for (int p = 0; p < 8; ++p) {
                const int tt = p * 64 + w * 8 + tsub;
                v4 ua = {0.f, 0.f, 0.f, 0.f}, ub = {0.f, 0.f, 0.f, 0.f};
                float part = 0.f;
                if (tt < TS) {
                    if (tt < UPH) {
                        ua = *(const v4*)(up_lds + tt * 68 + u0);
                        ub = *(const v4*)(up_lds + tt * 68 + u0 + 4);
                    } else {
                        const v4* ur = (const v4*)(up + ((size_t)b2 * TS + tt) * UPS + u0);
                        ua = ur[0];
                        ub = ur[1];
                    }
                    part = dot4(ua, hpA) + dot4(ub, hpB);
                }
                part += __shfl_xor(part, 1);
                part += __shfl_xor(part, 2);
                part += __shfl_xor(part, 4);
                const float s = (tt < TS) ? part : -1e30f;
                float M = s;
                M = fmaxf(M, __shfl_xor(M, 8));
                M = fmaxf(M, __shfl_xor(M, 16));
                M = fmaxf(M, __shfl_xor(M, 32));
                const float mn = fmaxf(mx, M);
                const float alpha = __expf(mx - mn);
                const float e = __expf(s - mn);
                float E = e;
                E += __shfl_xor(E, 8); E += __shfl_xor(E, 16); E += __shfl_xor(E, 32);
                S = S * alpha + E;
                mx = mn;
#pragma unroll
                for (int i = 0; i < 4; ++i) cx[i] = cx[i] * alpha + e * ua[i];
#pragma unroll
                for (int i = 0; i < 4; ++i) cx[4 + i] = cx[4 + i] * alpha + e * ub[i];
            }
#pragma unroll
            for (int i = 0; i < 8; ++i) {
                cx[i] += __shfl_xor(cx[i], 8);
                cx[i] += __shfl_xor(cx[i], 16);
                cx[i] += __shfl_xor(cx[i], 32);
            }
            if (tsub == 0) {
#pragma unroll
                for (int i = 0; i < 8; ++i) s_ctx[w][u0 + i] = cx[i];
            }
            if (lane == 0) { s_mw[w] = mx; s_Sw[w] = S; }
            __syncthreads();
            if (tid < UPS) {
                float M = s_mw[0];
                for (int i = 1; i < 8; ++i) M = fmaxf(M, s_mw[i]);
                float Sg = 0.f, c = 0.f;
                for (int i = 0; i < 8; ++i) {
                    const float f = __expf(s_mw[i] - M);
                    Sg += s_Sw[i] * f;
                    c += s_ctx[i][tid] * f;
                }
                pushf(uctxB + (size_t)b2 * UPS + tid, c / Sg);
            }
            wait_pull();
            __syncthreads();
            if (tid == 0) set_flag(uF + bid * 16, t + 1);
        }

        // ================= P3: uctx flags (h-tile safety transitive) + concat + logits =
        {
            if (tid < 8) {
                const int m = bs * 8 + tid;                       // uctx row we need
                spin_flag(uF + ((m & 31) * 8 + (m >> 5)) * 16, t + 1);
            }
            __syncthreads();
            {
                v4 aa = pull4(hP + (size_t)(bs * 8 + blp) * H + k4s * 4);
                v4 bb = pull4(hP + (size_t)(bs * 8 + blp + 1) * H + k4s * 4);
                const int uu = tid & 63, blu = tid >> 6;
                float uv = pullf(uctxB + (size_t)(bs * 8 + blu) * UPS + uu);
                wait_pull();
                s_h4[k4s * 9 + blp] = aa;
                s_h4[k4s * 9 + blp + 1] = bb;
                s_uctx[((uu >> 2) * 8 + blu) * 4 + (uu & 3)] = uv;
            }
            __syncthreads();
            {
                float acc[8];
#pragma unroll
                for (int bl = 0; bl < 8; ++bl) acc[bl] = 0.f;
                const int kbase = wk * 16;
#pragma unroll 4
                for (int kk = 0; kk < 16; ++kk) {
                    const int k4 = kbase + kk;
                    const v4 wv = wc4[k4 * 512 + j];
                    const v4* hrow = &s_h4[k4 * 9];
#pragma unroll
                    for (int bl = 0; bl < 8; ++bl) acc[bl] += dot4(hrow[bl], wv);
                }
#pragma unroll
                for (int ui = 0; ui < 2; ++ui) {
                    const int u4 = wk * 2 + ui;
                    const v4 wv = wf4[u4 * 512 + j];
#pragma unroll
                    for (int bl = 0; bl < 8; ++bl) acc[bl] += dot4(s_u4[u4 * 8 + bl], wv);
                }
                const int rb = wk * 1600 + jg * 25;
#pragma unroll
                for (int bl = 0; bl < 8; ++bl) s_red[rb + bl] = acc[bl];
            }
            __syncthreads();
            {
                const int bl = tid >> 6, jg2 = tid & 63;
                const int j2 = jx * 64 + jg2;
                float a = 0.f;
#pragma unroll
                for (int wk2 = 0; wk2 < 8; ++wk2) a += s_red[wk2 * 1600 + jg2 * 25 + bl];
                s_c[jg2 * 9 + bl] = tanhf(a + bcat2[j2]);
            }
            __syncthreads();
            if (tid < 200) {
                float a = 0.f;
                const float* wo = W_out + (size_t)lgv * H + jx * 64;
#pragma unroll 8
                for (int jj = 0; jj < 64; ++jj) a += s_c[jj * 9 + lgb] * wo[jj];
                pushf(lgp + ((size_t)jx * 256 + (bs * 8 + lgb)) * 25 + lgv, a);
            }
            wait_pull();
            __syncthreads();
            if (tid == 0) set_flag(lgF + bid * 16, t + 1);
        }
    }

    // ---- tail: final logits (t = TS-1) after all producers flagged ----
    if (tid < 8) spin_flag(lgF + (bs * 8 + tid) * 16, TS);
    __syncthreads();
    if (jx == 0 && tid < 200) {
        const int b = bs * 8 + lgb;
        float p0 = pullf(lgp + ((size_t)0 * 256 + b) * 25 + lgv);
        float p1 = pullf(lgp + ((size_t)1 * 256 + b) * 25 + lgv);
        float p2 = pullf(lgp + ((size_t)2 * 256 + b) * 25 + lgv);
        float p3 = pullf(lgp + ((size_t)3 * 256 + b) * 25 + lgv);
        float p4 = pullf(lgp + ((size_t)4 * 256 + b) * 25 + lgv);
        float p5 = pullf(lgp + ((size_t)5 * 256 + b) * 25 + lgv);
        float p6 = pullf(lgp + ((size_t)6 * 256 + b) * 25 + lgv);
        float p7 = pullf(lgp + ((size_t)7 * 256 + b) * 25 + lgv);
        wait_pull();
        float s = ((p0 + p1) + (p2 + p3)) + ((p4 + p5) + (p6 + p7)) + b_out[lgv];
        out[((size_t)b * V + lgv) * TS + (TS - 1)] = s;
    }
}

// ---------------- launcher ----------------

extern "C" void kernel_launch(void* const* d_in, const int* in_sizes, int n_in,
                              void* d_out, int out_size, void* d_ws, size_t ws_size,
                              hipStream_t stream) {
    const float* latent = (const float*)d_in[0];
    const float* up     = (const float*)d_in[1];
    const float* embed  = (const float*)d_in[2];
    const float* W_hid  = (const float*)d_in[3];
    const float* b_hid  = (const float*)d_in[4];
    const float* W_ih   = (const float*)d_in[5];
    const float* b_ih   = (const float*)d_in[6];
    const float* W_hh   = (const float*)d_in[7];
    const float* b_hh   = (const float*)d_in[8];
    const float* W_mem  = (const float*)d_in[9];
    const float* b_mem  = (const float*)d_in[10];
    const float* W_cat  = (const float*)d_in[11];
    const float* b_cat  = (const float*)d_in[12];
    const float* W_out  = (const float*)d_in[13];
    const float* b_out  = (const float*)d_in[14];
    float* out = (float*)d_out;
    float* ws = (float*)d_ws;

    k_init_egi<<<(V * 3 * H + 255) / 256, 256, 0, stream>>>(embed, W_ih, b_ih, ws + OFF_EGI);
    k_init_h0<<<NB, H, 0, stream>>>(latent, W_hid, b_hid, ws + OFF_HP);
    k_pack_whh<<<(1536 * 128 + 255) / 256, 256, 0, stream>>>(W_hh, ws + OFF_WHHQ);
    k_pack_wcat<<<(512 * 128 + 255) / 256, 256, 0, stream>>>(W_cat, ws + OFF_WCATQ);
    k_init_fold<<<(H * UPS + 255) / 256, 256, 0, stream>>>(W_cat, W_mem, ws + OFF_WFOLDQ);
    k_init_bcat<<<(H + 255) / 256, 256, 0, stream>>>(W_cat, b_mem, b_cat, ws + OFF_BCAT2);
    k_pack_wmem<<<(128 * 64 + 255) / 256, 256, 0, stream>>>(W_mem, ws + OFF_WMQ);
    k_init_flags<<<12, 1024, 0, stream>>>((int*)(ws + OFF_HF));

    k_main<<<NBLK, 512, 0, stream>>>(up, b_hh, W_out, b_out, out, ws);
}